// Round 2
// baseline (16284.943 us; speedup 1.0000x reference)
//
#include <hip/hip_runtime.h>
#include <cstdint>
#include <cstddef>

#define INP  40
#define HID  768
#define NG   3072      // 4*HID
#define NW   200       // windows
#define TS   160       // timesteps per window
#define GW   50        // windows per group
#define SGRP 4         // groups
#define NS   64        // gate slices
#define SH   12        // h-dims per slice
#define SR   48        // gate rows per slice (4*SH)

typedef __bf16 bf16x8 __attribute__((ext_vector_type(8)));
typedef float  f32x4  __attribute__((ext_vector_type(4)));

__device__ __forceinline__ unsigned short f2bf(float f) {
    unsigned u = __builtin_bit_cast(unsigned, f);
    unsigned r = ((u >> 16) & 1u) + 0x7fffu;   // RNE
    return (unsigned short)((u + r) >> 16);
}
__device__ __forceinline__ float bf2f(unsigned short h) {
    unsigned u = ((unsigned)h) << 16;
    return __builtin_bit_cast(float, u);
}
__device__ __forceinline__ float sigm(float x) { return 1.f / (1.f + expf(-x)); }

__global__ void zero_cnt(int* __restrict__ c) {
    int gid = blockIdx.x * 256 + threadIdx.x;            // 768
    c[gid] = 0;
}

// group barrier: 64 WGs per group, device-scope monotonic counter
__device__ __forceinline__ void group_barrier(int* bar, int target) {
    __threadfence();
    __syncthreads();
    if (threadIdx.x == 0) {
        __hip_atomic_fetch_add(bar, 1, __ATOMIC_RELEASE, __HIP_MEMORY_SCOPE_AGENT);
        while (__hip_atomic_load(bar, __ATOMIC_ACQUIRE, __HIP_MEMORY_SCOPE_AGENT) < target)
            __builtin_amdgcn_s_sleep(2);
    }
    __syncthreads();
}

// ---------------- persistent recurrent scan, fused input projection ----------------
// grid 256 = 64 slices (s) x 4 groups (g); block 256 = 4 waves.
// wave v owns M-tile v (windows 16v..16v+15 of the group; valid < 50),
// and all 48 gate cols (3 N-tiles of 16).
// slice s owns h-dims [12s, 12s+12) of each of the 4 gates:
//   packed row pl = chunk*12 + j  <->  original gate row = chunk*768 + s*12 + j
template <int LAYER>
__launch_bounds__(256, 1)
__global__ void lstm_scan(const float* __restrict__ whh,   // [3072][768] fp32
                          const float* __restrict__ wih,   // [3072][768] fp32 (layer0: [3072][40])
                          const float* __restrict__ b_ih,  // [3072]
                          const float* __restrict__ b_hh,  // [3072]
                          const unsigned short* __restrict__ prev, // prev-layer hist (layers 1,2)
                          const float* __restrict__ x,     // raw input (layer 0)
                          unsigned short* __restrict__ hist, // [TS+1][NW][HID] bf16
                          int* __restrict__ cnt)           // 4 groups x 64 ints
{
    __shared__ __align__(16) unsigned short Wh[SR * HID];  // 73728 B, swizzled
    __shared__ __align__(16) unsigned short Wi[SR * HID];  // 73728 B, swizzled
    __shared__ __align__(16) float gates[64 * SR];         // 12288 B
    __shared__ float cbuf[GW * SH];                        // 2400 B   (total 162144 <= 163840)

    const int tid  = threadIdx.x;
    const int bid  = blockIdx.x;
    const int g    = bid & 3;
    const int s    = bid >> 2;
    const int v    = tid >> 6;
    const int lane = tid & 63;
    const int m    = lane & 15;
    const int kg   = lane >> 4;
    const int wl_f = v * 16 + m;                 // 0..63, valid < 50
    const int w_f  = GW * g + wl_f;
    const int w_c  = (w_f > NW - 1) ? (NW - 1) : w_f;  // clamped (pad rows read real data, discarded)
    int* barg = cnt + g * 64;

    // stage W_hh (and W_ih for layers>=1) slice into LDS, fp32 -> bf16, XOR swizzle
    for (int idx = tid; idx < SR * (HID / 8); idx += 256) {
        int n = idx / (HID / 8), c8 = idx - n * (HID / 8);
        int orow = (n / SH) * HID + s * SH + (n % SH);
        const float* ph = whh + (size_t)orow * HID + c8 * 8;
        bf16x8 vh;
#pragma unroll
        for (int e = 0; e < 8; ++e) vh[e] = (__bf16)ph[e];
        *(bf16x8*)(&Wh[n * HID + (c8 ^ (n & 7)) * 8]) = vh;
        if constexpr (LAYER != 0) {
            const float* pi = wih + (size_t)orow * HID + c8 * 8;
            bf16x8 vi;
#pragma unroll
            for (int e = 0; e < 8; ++e) vi[e] = (__bf16)pi[e];
            *(bf16x8*)(&Wi[n * HID + (c8 ^ (n & 7)) * 8]) = vi;
        }
    }

    // zero c-state and own part of hist slot 0 (h_{-1} = 0)
    for (int i = tid; i < GW * SH; i += 256) {
        cbuf[i] = 0.f;
        int wl = i / SH, d = i - wl * SH;
        hist[(size_t)(GW * g + wl) * HID + s * SH + d] = 0;
    }

    // elementwise-phase biases (per thread, up to 3 owned elements x 4 gates)
    float bE[3][4];
#pragma unroll
    for (int ii = 0; ii < 3; ++ii) {
        int i = tid + ii * 256;
        if (i < GW * SH) {
            int d = i % SH;
            int hdim = s * SH + d;
#pragma unroll
            for (int c = 0; c < 4; ++c)
                bE[ii][c] = b_ih[c * HID + hdim] + b_hh[c * HID + hdim];
        }
    }

    // layer-0: persistent W_ih fragments in registers (K = 40 padded to 64)
    bf16x8 bih[3][2];
    if constexpr (LAYER == 0) {
#pragma unroll
        for (int nt = 0; nt < 3; ++nt) {
            int pl = nt * 16 + m;
            int orow = (pl / SH) * HID + s * SH + (pl % SH);
#pragma unroll
            for (int e = 0; e < 8; ++e) {
                int k0 = kg * 8 + e;
                int k1 = 32 + kg * 8 + e;
                bih[nt][0][e] = (k0 < INP) ? (__bf16)wih[(size_t)orow * INP + k0] : (__bf16)0.f;
                bih[nt][1][e] = (k1 < INP) ? (__bf16)wih[(size_t)orow * INP + k1] : (__bf16)0.f;
            }
        }
    }

    int target = NS;
    group_barrier(barg, target);

    for (int t = 0; t < TS; ++t) {
        f32x4 acc[3];
        const f32x4 zf = {0.f, 0.f, 0.f, 0.f};
#pragma unroll
        for (int nt = 0; nt < 3; ++nt) acc[nt] = zf;

        if constexpr (LAYER == 0) {
            // fused x @ W_ih0^T  (K=40 padded to 64)
            bf16x8 ax0 = (bf16x8)(__bf16)0.f, ax1 = (bf16x8)(__bf16)0.f;
            if (wl_f < GW) {
                const float* xr = x + (size_t)(80 * w_f + t) * INP;
                const float4* p0 = (const float4*)(xr + kg * 8);
                float4 u0 = p0[0], u1 = p0[1];
                ax0[0] = (__bf16)u0.x; ax0[1] = (__bf16)u0.y; ax0[2] = (__bf16)u0.z; ax0[3] = (__bf16)u0.w;
                ax0[4] = (__bf16)u1.x; ax0[5] = (__bf16)u1.y; ax0[6] = (__bf16)u1.z; ax0[7] = (__bf16)u1.w;
                if (kg == 0) {
                    const float4* p1 = (const float4*)(xr + 32);
                    float4 q0 = p1[0], q1 = p1[1];
                    ax1[0] = (__bf16)q0.x; ax1[1] = (__bf16)q0.y; ax1[2] = (__bf16)q0.z; ax1[3] = (__bf16)q0.w;
                    ax1[4] = (__bf16)q1.x; ax1[5] = (__bf16)q1.y; ax1[6] = (__bf16)q1.z; ax1[7] = (__bf16)q1.w;
                }
            }
#pragma unroll
            for (int nt = 0; nt < 3; ++nt) {
                acc[nt] = __builtin_amdgcn_mfma_f32_16x16x32_bf16(ax0, bih[nt][0], acc[nt], 0, 0, 0);
                acc[nt] = __builtin_amdgcn_mfma_f32_16x16x32_bf16(ax1, bih[nt][1], acc[nt], 0, 0, 0);
            }
        }

        // K-loop: recurrent h_{t-1} @ W_hh^T  (+ h_prev_layer(t) @ W_ih^T for layers 1,2)
        const unsigned short* hrow = hist + ((size_t)t * NW + w_c) * HID;
        const unsigned short* prow = nullptr;
        if constexpr (LAYER != 0)
            prow = prev + ((size_t)(t + 1) * NW + w_c) * HID;

#pragma unroll 4
        for (int kc = 0; kc < 24; ++kc) {
            bf16x8 ar = *(const bf16x8*)(hrow + kc * 32 + kg * 8);
            bf16x8 ax;
            if constexpr (LAYER != 0)
                ax = *(const bf16x8*)(prow + kc * 32 + kg * 8);
            int c8 = kc * 4 + kg;
#pragma unroll
            for (int nt = 0; nt < 3; ++nt) {
                int n = nt * 16 + m;
                bf16x8 bh = *(const bf16x8*)(&Wh[n * HID + (c8 ^ (n & 7)) * 8]);
                acc[nt] = __builtin_amdgcn_mfma_f32_16x16x32_bf16(ar, bh, acc[nt], 0, 0, 0);
                if constexpr (LAYER != 0) {
                    bf16x8 bx = *(const bf16x8*)(&Wi[n * HID + (c8 ^ (n & 7)) * 8]);
                    acc[nt] = __builtin_amdgcn_mfma_f32_16x16x32_bf16(ax, bx, acc[nt], 0, 0, 0);
                }
            }
        }

        // gates -> LDS (C layout: col = lane&15 = gate row, row = kg*4 + r = window)
#pragma unroll
        for (int nt = 0; nt < 3; ++nt) {
            int pl = nt * 16 + m;
#pragma unroll
            for (int r = 0; r < 4; ++r)
                gates[(v * 16 + kg * 4 + r) * SR + pl] = acc[nt][r];
        }
        __syncthreads();

        // elementwise LSTM cell update for owned (window, h-dim) pairs
#pragma unroll
        for (int ii = 0; ii < 3; ++ii) {
            int i = tid + ii * 256;
            if (i < GW * SH) {
                int wl = i / SH, d = i - wl * SH;
                float ig = gates[wl * SR + d]          + bE[ii][0];
                float fg = gates[wl * SR + SH + d]     + bE[ii][1];
                float gg = gates[wl * SR + 2 * SH + d] + bE[ii][2];
                float og = gates[wl * SR + 3 * SH + d] + bE[ii][3];
                float c = cbuf[i];
                c = sigm(fg) * c + sigm(ig) * tanhf(gg);
                float h = sigm(og) * tanhf(c);
                cbuf[i] = c;
                hist[((size_t)(t + 1) * NW + GW * g + wl) * HID + s * SH + d] = f2bf(h);
            }
        }
        target += NS;
        group_barrier(barg, target);
    }
}

// ---------------- output head ----------------
__global__ void out_y(const unsigned short* __restrict__ hist, const float* __restrict__ wout,
                      const float* __restrict__ bout, float* __restrict__ yn) {
    __shared__ float hv[HID];
    __shared__ float red[256];
    const int w = blockIdx.x, tid = threadIdx.x;
    for (int i = tid; i < HID; i += 256)
        hv[i] = bf2f(hist[((size_t)TS * NW + w) * HID + i]);
    __syncthreads();
    float acc = bout[tid];
    const float* wr = wout + (size_t)tid * HID;
    for (int k = 0; k < HID; ++k) acc += hv[k] * wr[k];
    red[tid] = acc * acc;
    __syncthreads();
    for (int off = 128; off > 0; off >>= 1) {
        if (tid < off) red[tid] += red[tid + off];
        __syncthreads();
    }
    float inv = 1.f / sqrtf(red[0]);
    yn[w * 256 + tid] = acc * inv;
}

__global__ void out_reduce(const float* __restrict__ yn, float* __restrict__ out) {
    const int o = threadIdx.x;
    float s = 0.f;
    for (int w = 0; w < NW; ++w) s += yn[w * 256 + o];
    out[o] = s * (1.f / NW);
}

// ---------------- host ----------------
extern "C" void kernel_launch(void* const* d_in, const int* in_sizes, int n_in,
                              void* d_out, int out_size, void* d_ws, size_t ws_size,
                              hipStream_t stream) {
    (void)in_sizes; (void)n_in; (void)out_size;
    const float* x    = (const float*)d_in[0];
    const float* wih0 = (const float*)d_in[1];
    const float* whh0 = (const float*)d_in[2];
    const float* bi0  = (const float*)d_in[3];
    const float* bh0  = (const float*)d_in[4];
    const float* wih1 = (const float*)d_in[5];
    const float* whh1 = (const float*)d_in[6];
    const float* bi1  = (const float*)d_in[7];
    const float* bh1  = (const float*)d_in[8];
    const float* wih2 = (const float*)d_in[9];
    const float* whh2 = (const float*)d_in[10];
    const float* bi2  = (const float*)d_in[11];
    const float* bh2  = (const float*)d_in[12];
    const float* wout = (const float*)d_in[13];
    const float* bout = (const float*)d_in[14];

    char* base = (char*)d_ws;
    size_t off = 0;
    auto take = [&](size_t bytes) { size_t r = off; off += (bytes + 255) & ~(size_t)255; return r; };
    unsigned short* HA  = (unsigned short*)(base + take((size_t)(TS + 1) * NW * HID * 2)); // 49.5 MB
    unsigned short* HB  = (unsigned short*)(base + take((size_t)(TS + 1) * NW * HID * 2)); // 49.5 MB
    int*            CNT = (int*)(base + take(768UL * 4));
    float*          YN  = (float*)(base + take((size_t)NW * 256 * 4));
    if (ws_size < off) return;  // ~99 MB needed; leave d_out zeroed (visible failure)

    zero_cnt<<<dim3(3), dim3(256), 0, stream>>>(CNT);

    lstm_scan<0><<<dim3(256), dim3(256), 0, stream>>>(whh0, wih0, bi0, bh0, nullptr, x, HA, CNT);
    lstm_scan<1><<<dim3(256), dim3(256), 0, stream>>>(whh1, wih1, bi1, bh1, HA, nullptr, HB, CNT + 256);
    lstm_scan<2><<<dim3(256), dim3(256), 0, stream>>>(whh2, wih2, bi2, bh2, HB, nullptr, HA, CNT + 512);

    out_y<<<dim3(NW), dim3(256), 0, stream>>>(HA, wout, bout, YN);
    out_reduce<<<dim3(1), dim3(256), 0, stream>>>(YN, (float*)d_out);
}

// Round 4
// 5986.168 us; speedup vs baseline: 2.7204x; 2.7204x over previous
//
#include <hip/hip_runtime.h>
#include <cstdint>
#include <cstddef>

#define INP  40
#define HID  768
#define NG   3072      // 4*HID
#define NW   200       // windows
#define TS   160       // timesteps per window
#define GW   50        // windows per group
#define NS   64        // gate slices
#define SH   12        // h-dims per slice
#define SR   48        // gate rows per slice (4*SH)
#define GS   52        // gates LDS row stride (floats): bank-conflict-free (2-way max)

typedef __bf16 bf16x8 __attribute__((ext_vector_type(8)));
typedef float  f32x4  __attribute__((ext_vector_type(4)));

__device__ __forceinline__ unsigned short f2bf(float f) {
    unsigned u = __builtin_bit_cast(unsigned, f);
    unsigned r = ((u >> 16) & 1u) + 0x7fffu;   // RNE
    return (unsigned short)((u + r) >> 16);
}
__device__ __forceinline__ float bf2f(unsigned short h) {
    unsigned u = ((unsigned)h) << 16;
    return __builtin_bit_cast(float, u);
}
__device__ __forceinline__ float sigm(float x) { return 1.f / (1.f + expf(-x)); }

__global__ void zero_cnt(int* __restrict__ c) {
    int gid = blockIdx.x * 256 + threadIdx.x;            // 6144 (3 layers x 4 groups x 512)
    c[gid] = 0;
}

// ---- tree barrier: 64 WGs/group; 8 sub-counters (by s&7) -> root -> epoch flag ----
// layout per group (512 ints): sub[j] at j*32, root at 256, epoch at 288
__device__ __forceinline__ void group_barrier(int* base, int s, int t1) {
    __syncthreads();   // all threads' (agent-bypass) hist stores drained (vmcnt) before arrival
    if (threadIdx.x == 0) {
        int* sub = base + (s & 7) * 32;
        int old = __hip_atomic_fetch_add(sub, 1, __ATOMIC_RELEASE, __HIP_MEMORY_SCOPE_AGENT);
        if (old == t1 * 8 - 1) {
            int ro = __hip_atomic_fetch_add(base + 256, 1, __ATOMIC_ACQ_REL, __HIP_MEMORY_SCOPE_AGENT);
            if (ro == t1 * 8 - 1)
                __hip_atomic_store(base + 288, t1, __ATOMIC_RELEASE, __HIP_MEMORY_SCOPE_AGENT);
        }
        while (__hip_atomic_load(base + 288, __ATOMIC_RELAXED, __HIP_MEMORY_SCOPE_AGENT) < t1)
            __builtin_amdgcn_s_sleep(8);
        __builtin_amdgcn_fence(__ATOMIC_ACQUIRE, "agent");  // invalidate stale L1/L2 lines
    }
    __syncthreads();
}

// ---------------- persistent recurrent scan, fused input projection ----------------
// grid 256 = 64 slices (s) x 4 groups (g); block 256 = 4 waves.
// wave v owns M-tile v (windows 16v..16v+15 of the group; valid < 50), all 48 gate cols.
// slice s owns h-dims [12s,12s+12): packed row pl = chunk*12 + j <-> gate row chunk*768 + s*12 + j
template <int LAYER>
__launch_bounds__(256, 1)
__global__ void lstm_scan(const float* __restrict__ whh,   // [3072][768] fp32
                          const float* __restrict__ wih,   // [3072][768] fp32 (layer0: [3072][40])
                          const float* __restrict__ b_ih,  // [3072]
                          const float* __restrict__ b_hh,  // [3072]
                          const unsigned short* __restrict__ prev, // prev-layer hist (layers 1,2)
                          const float* __restrict__ x,     // raw input (layer 0)
                          unsigned short* __restrict__ hist, // [TS+1][NW][HID] bf16
                          int* __restrict__ cnt)           // THIS LAYER's 4 groups x 512 ints
{
    __shared__ __align__(16) unsigned short Wh[SR * HID];  // 73728 B, swizzled
    __shared__ __align__(16) unsigned short Wi[SR * HID];  // 73728 B, swizzled
    __shared__ __align__(16) float gates[64 * GS];         // 13312 B
    __shared__ float cbuf[GW * SH];                        // 2400 B   (total 163168 <= 163840)

    const int tid  = threadIdx.x;
    const int bid  = blockIdx.x;
    const int g    = bid & 3;
    const int s    = bid >> 2;
    const int v    = tid >> 6;
    const int lane = tid & 63;
    const int m    = lane & 15;
    const int kg   = lane >> 4;
    const int wl_f = v * 16 + m;                 // 0..63, valid < 50
    const int w_f  = GW * g + wl_f;
    const int w_c  = (w_f > NW - 1) ? (NW - 1) : w_f;  // clamped (pad rows read real data, discarded)
    int* barg = cnt + g * 512;

    // stage W_hh (and W_ih for layers>=1) slice into LDS, fp32 -> bf16, XOR swizzle
    for (int idx = tid; idx < SR * (HID / 8); idx += 256) {
        int n = idx / (HID / 8), c8 = idx - n * (HID / 8);
        int orow = (n / SH) * HID + s * SH + (n % SH);
        const float* ph = whh + (size_t)orow * HID + c8 * 8;
        bf16x8 vh;
#pragma unroll
        for (int e = 0; e < 8; ++e) vh[e] = (__bf16)ph[e];
        *(bf16x8*)(&Wh[n * HID + (c8 ^ (n & 7)) * 8]) = vh;
        if constexpr (LAYER != 0) {
            const float* pi = wih + (size_t)orow * HID + c8 * 8;
            bf16x8 vi;
#pragma unroll
            for (int e = 0; e < 8; ++e) vi[e] = (__bf16)pi[e];
            *(bf16x8*)(&Wi[n * HID + (c8 ^ (n & 7)) * 8]) = vi;
        }
    }

    // zero c-state and own part of hist slot 0 (h_{-1}=0), agent-bypass packed stores
    for (int i = tid; i < GW * SH / 2; i += 256) {     // 300 u32 pairs
        int wl = i / (SH / 2), dp = i - wl * (SH / 2);
        cbuf[wl * SH + 2 * dp] = 0.f;
        cbuf[wl * SH + 2 * dp + 1] = 0.f;
        unsigned* hp = (unsigned*)(hist + (size_t)(GW * g + wl) * HID + s * SH) + dp;
        __hip_atomic_store(hp, 0u, __ATOMIC_RELAXED, __HIP_MEMORY_SCOPE_AGENT);
    }

    // elementwise-phase biases (per thread, up to 2 owned pairs x 4 gates x 2 dims)
    float bE[2][4][2];
#pragma unroll
    for (int ii = 0; ii < 2; ++ii) {
        int p = tid + ii * 256;
        if (p < GW * SH / 2) {
            int dp = p % (SH / 2);
            int hd0 = s * SH + 2 * dp;
#pragma unroll
            for (int c = 0; c < 4; ++c) {
                bE[ii][c][0] = b_ih[c * HID + hd0] + b_hh[c * HID + hd0];
                bE[ii][c][1] = b_ih[c * HID + hd0 + 1] + b_hh[c * HID + hd0 + 1];
            }
        }
    }

    // layer-0: persistent W_ih fragments in registers (K = 40 padded to 64)
    bf16x8 bih[3][2];
    if constexpr (LAYER == 0) {
#pragma unroll
        for (int nt = 0; nt < 3; ++nt) {
            int pl = nt * 16 + m;
            int orow = (pl / SH) * HID + s * SH + (pl % SH);
#pragma unroll
            for (int e = 0; e < 8; ++e) {
                int k0 = kg * 8 + e;
                int k1 = 32 + kg * 8 + e;
                bih[nt][0][e] = (k0 < INP) ? (__bf16)wih[(size_t)orow * INP + k0] : (__bf16)0.f;
                bih[nt][1][e] = (k1 < INP) ? (__bf16)wih[(size_t)orow * INP + k1] : (__bf16)0.f;
            }
        }
    }

    group_barrier(barg, s, 1);

    for (int t = 0; t < TS; ++t) {
        f32x4 acc[3];
        const f32x4 zf = {0.f, 0.f, 0.f, 0.f};
#pragma unroll
        for (int nt = 0; nt < 3; ++nt) acc[nt] = zf;

        if constexpr (LAYER == 0) {
            // fused x @ W_ih0^T  (K=40 padded to 64)
            bf16x8 ax0 = (bf16x8)(__bf16)0.f, ax1 = (bf16x8)(__bf16)0.f;
            if (wl_f < GW) {
                const float* xr = x + (size_t)(80 * w_f + t) * INP;
                const float4* p0 = (const float4*)(xr + kg * 8);
                float4 u0 = p0[0], u1 = p0[1];
                ax0[0] = (__bf16)u0.x; ax0[1] = (__bf16)u0.y; ax0[2] = (__bf16)u0.z; ax0[3] = (__bf16)u0.w;
                ax0[4] = (__bf16)u1.x; ax0[5] = (__bf16)u1.y; ax0[6] = (__bf16)u1.z; ax0[7] = (__bf16)u1.w;
                if (kg == 0) {
                    const float4* p1 = (const float4*)(xr + 32);
                    float4 q0 = p1[0], q1 = p1[1];
                    ax1[0] = (__bf16)q0.x; ax1[1] = (__bf16)q0.y; ax1[2] = (__bf16)q0.z; ax1[3] = (__bf16)q0.w;
                    ax1[4] = (__bf16)q1.x; ax1[5] = (__bf16)q1.y; ax1[6] = (__bf16)q1.z; ax1[7] = (__bf16)q1.w;
                }
            }
#pragma unroll
            for (int nt = 0; nt < 3; ++nt) {
                acc[nt] = __builtin_amdgcn_mfma_f32_16x16x32_bf16(ax0, bih[nt][0], acc[nt], 0, 0, 0);
                acc[nt] = __builtin_amdgcn_mfma_f32_16x16x32_bf16(ax1, bih[nt][1], acc[nt], 0, 0, 0);
            }
        }

        // K-loop: h_{t-1} @ W_hh^T  (+ h_prev_layer(t) @ W_ih^T for layers 1,2)
        const unsigned short* hrow = hist + ((size_t)t * NW + w_c) * HID;
        const unsigned short* prow = nullptr;
        if constexpr (LAYER != 0)
            prow = prev + ((size_t)(t + 1) * NW + w_c) * HID;

#pragma unroll 4
        for (int kc = 0; kc < 24; ++kc) {
            bf16x8 ar = *(const bf16x8*)(hrow + kc * 32 + kg * 8);
            bf16x8 ax;
            if constexpr (LAYER != 0)
                ax = *(const bf16x8*)(prow + kc * 32 + kg * 8);
            int c8 = kc * 4 + kg;
#pragma unroll
            for (int nt = 0; nt < 3; ++nt) {
                int n = nt * 16 + m;
                bf16x8 bh = *(const bf16x8*)(&Wh[n * HID + (c8 ^ (n & 7)) * 8]);
                acc[nt] = __builtin_amdgcn_mfma_f32_16x16x32_bf16(ar, bh, acc[nt], 0, 0, 0);
                if constexpr (LAYER != 0) {
                    bf16x8 bx = *(const bf16x8*)(&Wi[n * HID + (c8 ^ (n & 7)) * 8]);
                    acc[nt] = __builtin_amdgcn_mfma_f32_16x16x32_bf16(ax, bx, acc[nt], 0, 0, 0);
                }
            }
        }

        // gates -> LDS (C layout: col = m = gate row, row = kg*4 + r = window), stride GS
#pragma unroll
        for (int nt = 0; nt < 3; ++nt) {
            int pl = nt * 16 + m;
#pragma unroll
            for (int r = 0; r < 4; ++r)
                gates[(v * 16 + kg * 4 + r) * GS + pl] = acc[nt][r];
        }
        __syncthreads();

        // elementwise LSTM cell update: 300 (window, dim-pair) items
#pragma unroll
        for (int ii = 0; ii < 2; ++ii) {
            int p = tid + ii * 256;
            if (p < GW * SH / 2) {
                int wl = p / (SH / 2), dp = p - wl * (SH / 2);
                int d0 = 2 * dp;
                unsigned hv;
#pragma unroll
                for (int e = 0; e < 2; ++e) {
                    int d = d0 + e;
                    float ig = gates[wl * GS + d]          + bE[ii][0][e];
                    float fg = gates[wl * GS + SH + d]     + bE[ii][1][e];
                    float gg = gates[wl * GS + 2 * SH + d] + bE[ii][2][e];
                    float og = gates[wl * GS + 3 * SH + d] + bE[ii][3][e];
                    float c = cbuf[wl * SH + d];
                    c = sigm(fg) * c + sigm(ig) * tanhf(gg);
                    float h = sigm(og) * tanhf(c);
                    cbuf[wl * SH + d] = c;
                    unsigned short hb = f2bf(h);
                    if (e == 0) hv = hb;
                    else        hv |= ((unsigned)hb) << 16;
                }
                unsigned* hp = (unsigned*)(hist + ((size_t)(t + 1) * NW + GW * g + wl) * HID + s * SH) + dp;
                __hip_atomic_store(hp, hv, __ATOMIC_RELAXED, __HIP_MEMORY_SCOPE_AGENT);
            }
        }
        if (t != TS - 1) group_barrier(barg, s, t + 2);
    }
}

// ---------------- output head ----------------
__global__ void out_y(const unsigned short* __restrict__ hist, const float* __restrict__ wout,
                      const float* __restrict__ bout, float* __restrict__ yn) {
    __shared__ float hv[HID];
    __shared__ float red[256];
    const int w = blockIdx.x, tid = threadIdx.x;
    for (int i = tid; i < HID; i += 256)
        hv[i] = bf2f(hist[((size_t)TS * NW + w) * HID + i]);
    __syncthreads();
    float acc = bout[tid];
    const float* wr = wout + (size_t)tid * HID;
    for (int k = 0; k < HID; ++k) acc += hv[k] * wr[k];
    red[tid] = acc * acc;
    __syncthreads();
    for (int off = 128; off > 0; off >>= 1) {
        if (tid < off) red[tid] += red[tid + off];
        __syncthreads();
    }
    float inv = 1.f / sqrtf(red[0]);
    yn[w * 256 + tid] = acc * inv;
}

__global__ void out_reduce(const float* __restrict__ yn, float* __restrict__ out) {
    const int o = threadIdx.x;
    float s = 0.f;
    for (int w = 0; w < NW; ++w) s += yn[w * 256 + o];
    out[o] = s * (1.f / NW);
}

// ---------------- host ----------------
extern "C" void kernel_launch(void* const* d_in, const int* in_sizes, int n_in,
                              void* d_out, int out_size, void* d_ws, size_t ws_size,
                              hipStream_t stream) {
    (void)in_sizes; (void)n_in; (void)out_size;
    const float* x    = (const float*)d_in[0];
    const float* wih0 = (const float*)d_in[1];
    const float* whh0 = (const float*)d_in[2];
    const float* bi0  = (const float*)d_in[3];
    const float* bh0  = (const float*)d_in[4];
    const float* wih1 = (const float*)d_in[5];
    const float* whh1 = (const float*)d_in[6];
    const float* bi1  = (const float*)d_in[7];
    const float* bh1  = (const float*)d_in[8];
    const float* wih2 = (const float*)d_in[9];
    const float* whh2 = (const float*)d_in[10];
    const float* bi2  = (const float*)d_in[11];
    const float* bh2  = (const float*)d_in[12];
    const float* wout = (const float*)d_in[13];
    const float* bout = (const float*)d_in[14];

    char* base = (char*)d_ws;
    size_t off = 0;
    auto take = [&](size_t bytes) { size_t r = off; off += (bytes + 255) & ~(size_t)255; return r; };
    unsigned short* HA  = (unsigned short*)(base + take((size_t)(TS + 1) * NW * HID * 2)); // 49.5 MB
    unsigned short* HB  = (unsigned short*)(base + take((size_t)(TS + 1) * NW * HID * 2)); // 49.5 MB
    int*            CNT = (int*)(base + take(3UL * 2048 * 4));   // PER-LAYER: 3 x (4 groups x 512)
    float*          YN  = (float*)(base + take((size_t)NW * 256 * 4));
    if (ws_size < off) return;  // ~99 MB needed; leave d_out zeroed (visible failure)

    zero_cnt<<<dim3(24), dim3(256), 0, stream>>>(CNT);

    lstm_scan<0><<<dim3(256), dim3(256), 0, stream>>>(whh0, wih0, bi0, bh0, nullptr, x, HA, CNT);
    lstm_scan<1><<<dim3(256), dim3(256), 0, stream>>>(whh1, wih1, bi1, bh1, HA, nullptr, HB, CNT + 2048);
    lstm_scan<2><<<dim3(256), dim3(256), 0, stream>>>(whh2, wih2, bi2, bh2, HB, nullptr, HA, CNT + 4096);

    out_y<<<dim3(NW), dim3(256), 0, stream>>>(HA, wout, bout, YN);
    out_reduce<<<dim3(1), dim3(256), 0, stream>>>(YN, (float*)d_out);
}